// Round 13
// baseline (167.503 us; speedup 1.0000x reference)
//
#include <hip/hip_runtime.h>

// Problem constants
#define Bn   16
#define Fn   48
#define Hn   256
#define Wn   256
#define Mn   51

#define TW    32
#define STRIP 64            // output rows per block (4 waves x 16-row bands)
#define BAND  16            // output rows per wave
#define NSUB  22            // a-rows per wave (BAND + 6)
#define DUPR  77            // staged input rows (STRIP + 13)
#define DUP_S 55            // dup-array row stride in dwords
#define C2ST  58            // c2 row stride in shorts (dword stride 29, odd -> bank spread)
#define C2DW  29

// Workspace layout (floats)
#define WS_SUMSQ 0
#define WS_FRG   16                 // 14 tiles * 64 lanes * uint4 = 3584 floats
#define WS_TABB  3600               // filter-major bf16 LUT: tab[f][idx]
#define TAB_N    8001
#define TAB_S    8004

typedef short short8 __attribute__((ext_vector_type(8)));
typedef float f32x4 __attribute__((ext_vector_type(4)));

__device__ __forceinline__ float waveReduceSum(float v) {
    #pragma unroll
    for (int o = 32; o > 0; o >>= 1) v += __shfl_xor(v, o);
    return v;
}

__device__ __forceinline__ unsigned short f2bf(float x) {
    unsigned int u = __builtin_bit_cast(unsigned int, x);
    unsigned int r = (u + 0x7FFFu + ((u >> 16) & 1u)) >> 16;
    return (unsigned short)r;
}

// pack two f32 -> bf16x2 (round-half-up): 3 VALU ops via v_perm_b32
__device__ __forceinline__ unsigned pk_bf2(float lo, float hi) {
    unsigned ulo = __builtin_bit_cast(unsigned, lo) + 0x8000u;
    unsigned uhi = __builtin_bit_cast(unsigned, hi) + 0x8000u;
    return __builtin_amdgcn_perm(uhi, ulo, 0x07060302u);  // D = [uhi.hi16, ulo.hi16]
}

// ---- setup: block 0 = weight prep + MFMA fragments; blocks 1.. = filter-major RBF LUT ----
__global__ __launch_bounds__(256) void setup_kernel(const float* __restrict__ cw,
                                                    const float* __restrict__ sf,
                                                    const float* __restrict__ rw,
                                                    const float* __restrict__ rc,
                                                    float* __restrict__ ws) {
    const int tid = threadIdx.x;
    if (blockIdx.x == 0) {
        __shared__ float s_wn[Fn * 49];
        const int lane = tid & 63;
        const int wv = tid >> 6;
        for (int i = 0; i < 12; ++i) {
            int f = wv * 12 + i;
            float v = (lane < 49) ? cw[f * 49 + lane] : 0.f;
            float mean = waveReduceSum(v) * (1.0f / 49.0f);
            float c = (lane < 49) ? (v - mean) : 0.f;
            float nrm = sqrtf(waveReduceSum(c * c));
            if (lane < 49) s_wn[f * 49 + lane] = sf[f] * c / (nrm + 1e-12f);
        }
        if (tid < 16) ws[WS_SUMSQ + tid] = 0.f;
        __syncthreads();
        if (wv == 0) {
            const int quad = lane >> 4, l15 = lane & 15;
            uint4* frg = (uint4*)(ws + WS_FRG);
            // z-GEMM A: A[m=filter][k=tap2], tap2 = ky*8+kx
            for (int mt = 0; mt < 3; ++mt)
                for (int kt = 0; kt < 2; ++kt) {
                    unsigned int pk[4] = {0, 0, 0, 0};
                    int f = mt * 16 + l15;
                    for (int j = 0; j < 8; ++j) {
                        int k = kt * 32 + quad * 8 + j;
                        int ky = k >> 3, kx = k & 7;
                        float v = (ky < 7 && kx < 7) ? s_wn[f * 49 + ky * 7 + kx] : 0.f;
                        pk[j >> 1] |= (unsigned int)f2bf(v) << (16 * (j & 1));
                    }
                    frg[(mt * 2 + kt) * 64 + lane] = make_uint4(pk[0], pk[1], pk[2], pk[3]);
                }
            // c-GEMM A2: A2[m][k=filter], m = p*8+q (q==7 or m>=56 -> zero row)
            for (int mt = 0; mt < 4; ++mt)
                for (int kt = 0; kt < 2; ++kt) {
                    unsigned int pk[4] = {0, 0, 0, 0};
                    int m = mt * 16 + l15;
                    int p = m >> 3, q = m & 7;
                    for (int j = 0; j < 8; ++j) {
                        int f = kt * 32 + quad * 8 + j;
                        float v = (p < 7 && q < 7 && f < 48)
                                  ? s_wn[f * 49 + (6 - p) * 7 + (6 - q)] : 0.f;
                        pk[j >> 1] |= (unsigned int)f2bf(v) << (16 * (j & 1));
                    }
                    frg[(6 + mt * 2 + kt) * 64 + lane] = make_uint4(pk[0], pk[1], pk[2], pk[3]);
                }
        }
    } else {
        // filter-major LUT: tab[f*TAB_S + idx] = bf16(g_f(-100 + 0.025*idx))
        int b = blockIdx.x - 1;
        int f = b >> 5;
        int idx = ((b & 31) << 8) + tid;
        if (idx < TAB_N) {
            float x = -100.0f + 0.025f * (float)idx;
            float g = 0.f;
            for (int m = 0; m < Mn; ++m) {
                float d = x - rc[m];
                g += rw[f * Mn + m] * __expf(-0.01f * d * d);
            }
            unsigned short* tab = (unsigned short*)(ws + WS_TABB);
            tab[f * TAB_S + idx] = f2bf(g);
        }
    }
}

// ---- fused MFMA kernel: 16-row bands, row-level gather double-buffer ----
__global__ __launch_bounds__(256) void fused_kernel(const float* __restrict__ input,
                                                    const float* __restrict__ net,
                                                    float* __restrict__ ws,
                                                    float* __restrict__ rout) {
    __shared__ unsigned int s_dup[DUPR * DUP_S];
    __shared__ __align__(16) unsigned short s_a[4][16 * 64];
    __shared__ __align__(8) unsigned short s_c2[4][48 * C2ST];   // per-wave [ax][m=p*8+q] bf16
    __shared__ float s_red[4];

    const int tid = threadIdx.x;
    const int lane = tid & 63;
    const int wv = tid >> 6;
    const int quad = lane >> 4;
    const int l15 = lane & 15;
    const int q4 = quad * 4;
    const int hl = lane >> 5;
    const int OX = lane & 31;
    const int bz = blockIdx.z;
    const int gy0 = blockIdx.y * STRIP;
    const int tx0 = blockIdx.x * TW;
    const float* img = input + bz * (Hn * Wn);
    const float* netb = net + bz * (Hn * Wn);
    float* rb = rout + bz * (Hn * Wn);

    // stage dup array: 77 rows x 55 dwords; dword i = (bf16 x[i], bf16 x[i+1]); sym pad
    for (int k = tid; k < DUPR * DUP_S; k += 256) {
        int j = k / DUP_S, i = k - j * DUP_S;
        int gy = gy0 - 6 + j;
        gy = (gy < 0) ? (-1 - gy) : ((gy > 255) ? (511 - gy) : gy);
        int gx0 = tx0 - 6 + i, gx1 = gx0 + 1;
        gx0 = (gx0 < 0) ? (-1 - gx0) : ((gx0 > 255) ? (511 - gx0) : gx0);
        gx1 = (gx1 < 0) ? (-1 - gx1) : ((gx1 > 255) ? (511 - gx1) : gx1);
        s_dup[j * DUP_S + i] = pk_bf2(img[gy * Wn + gx0], img[gy * Wn + gx1]);
    }
    // zero ALL of s_a (blocks 6..7 are MFMA B-operands never written; 0*garbage = NaN)
    {
        unsigned int* sa32 = (unsigned int*)s_a;
        for (int k = tid; k < 2048; k += 256) sa32[k] = 0u;
    }
    __syncthreads();

    // constant weight fragments
    const uint4* frg = (const uint4*)(ws + WS_FRG);
    short8 Afz[3][2], Afc[4][2];
    #pragma unroll
    for (int mt = 0; mt < 3; ++mt)
        #pragma unroll
        for (int kt = 0; kt < 2; ++kt)
            Afz[mt][kt] = __builtin_bit_cast(short8, frg[(mt * 2 + kt) * 64 + lane]);
    #pragma unroll
    for (int mt = 0; mt < 4; ++mt)
        #pragma unroll
        for (int kt = 0; kt < 2; ++kt)
            Afc[mt][kt] = __builtin_bit_cast(short8, frg[(6 + mt * 2 + kt) * 64 + lane]);

    const unsigned short* tab = (const unsigned short*)(ws + WS_TABB);
    const int fq = q4 * TAB_S;
    unsigned short* sa = s_a[wv];
    unsigned short* c2w = s_c2[wv];
    unsigned int* c2d = (unsigned int*)c2w;
    int wOff[3], rOff[2];
    #pragma unroll
    for (int mt = 0; mt < 3; ++mt)
        wOff[mt] = l15 * 64 + (((2 * mt + (quad >> 1)) ^ (l15 & 7)) * 8) + (quad & 1) * 4;
    #pragma unroll
    for (int kt = 0; kt < 2; ++kt)
        rOff[kt] = l15 * 64 + (((4 * kt + quad) ^ (l15 & 7)) * 8);

    const int A0 = wv * BAND;
    float w[4] = {0.f, 0.f, 0.f, 0.f};
    float rsq = 0.f;

    // zg: dup-reads -> z-MFMA -> issue 12 filter-major LUT gathers (results pend in g[])
    auto zg = [&](int aIdx, int nt, unsigned* g) {
        const int nt16 = nt * 16;
        const unsigned* dp0 = &s_dup[(aIdx + quad) * DUP_S + l15 + nt16];
        const unsigned* dp1 = dp0 + 4 * DUP_S;
        short8 B0 = __builtin_bit_cast(short8, make_uint4(dp0[0], dp0[2], dp0[4], dp0[6]));
        short8 B1 = __builtin_bit_cast(short8, make_uint4(dp1[0], dp1[2], dp1[4], dp1[6]));
        #pragma unroll
        for (int mt = 0; mt < 3; ++mt) {
            f32x4 z = {0.f, 0.f, 0.f, 0.f};
            z = __builtin_amdgcn_mfma_f32_16x16x32_bf16(Afz[mt][0], B0, z, 0, 0, 0);
            z = __builtin_amdgcn_mfma_f32_16x16x32_bf16(Afz[mt][1], B1, z, 0, 0, 0);
            #pragma unroll
            for (int r = 0; r < 4; ++r) {
                float tt = __builtin_amdgcn_fmed3f(
                    fmaf(z[r], 40.0f, 4000.5f), 0.0f, 8000.0f);
                g[mt * 4 + r] = tab[fq + (mt * 16 + r) * TAB_S + (int)tt];
            }
        }
    };

    // consume: pack -> s_a roundtrip -> convT MFMA -> C2 stores
    auto consume = [&](int nt, const unsigned* g, bool vy) {
        const int nt16 = nt * 16;
        const int ax = l15 + nt16;
        const unsigned msk = (vy && ((unsigned)(tx0 - 3 + ax) < (unsigned)Wn))
                             ? 0xFFFFFFFFu : 0u;
        #pragma unroll
        for (int mt = 0; mt < 3; ++mt) {
            unsigned lo = (g[mt * 4 + 0] | (g[mt * 4 + 1] << 16)) & msk;
            unsigned hi = (g[mt * 4 + 2] | (g[mt * 4 + 3] << 16)) & msk;
            *(uint2*)&sa[wOff[mt]] = make_uint2(lo, hi);
        }
        short8 B20 = *(const short8*)&sa[rOff[0]];
        short8 B21 = *(const short8*)&sa[rOff[1]];
        f32x4 d2[4];
        #pragma unroll
        for (int mt = 0; mt < 4; ++mt) {
            f32x4 c0 = {0.f, 0.f, 0.f, 0.f};
            c0 = __builtin_amdgcn_mfma_f32_16x16x32_bf16(Afc[mt][0], B20, c0, 0, 0, 0);
            c0 = __builtin_amdgcn_mfma_f32_16x16x32_bf16(Afc[mt][1], B21, c0, 0, 0, 0);
            d2[mt] = c0;
        }
        const int rowdw = ax * C2DW;
        #pragma unroll
        for (int mt = 0; mt < 4; ++mt) {
            unsigned lo = pk_bf2(d2[mt][0], d2[mt][1]);
            unsigned hi = pk_bf2(d2[mt][2], d2[mt][3]);
            const int cd = rowdw + mt * 8 + 2 * quad;
            if (mt < 3) {
                c2d[cd] = lo;
                c2d[cd + 1] = hi;
            } else if (quad < 2) {    // m=56..63 junk rows; cols would overflow stride
                c2d[cd] = lo;
                c2d[cd + 1] = hi;
            }
        }
    };

    // subiter: consumes gather set Gc (row i), prefetches row i+1 into Np
    auto subiter = [&](int i, bool even, unsigned (&Gc)[3][12], unsigned (&Np)[3][12]) {
        const int aIdx = A0 + i;
        const bool vy = ((unsigned)(gy0 - 3 + aIdx) < (unsigned)Hn);
        const int aN = A0 + ((i + 1 < NSUB) ? i + 1 : i);   // clamped prefetch row

        zg(aN, 0, Np[0]);
        consume(0, Gc[0], vy);
        zg(aN, 1, Np[1]);
        consume(1, Gc[1], vy);
        zg(aN, 2, Np[2]);
        consume(2, Gc[2], vy);

        // ---- q-gather into register window (band-edge masks: 0 <= out = i-p <= BAND-1) ----
        const bool laneE = even ? (hl == 0) : (hl != 0);
        #pragma unroll
        for (int j = 0; j < 4; ++j) {
            const int pe = 2 * j, po = 2 * j + 1;
            const bool liveE = (pe <= i) && (pe >= i - (BAND - 1));
            const bool liveO = (j < 3) && (po <= i) && (po >= i - (BAND - 1));
            if (liveE || liveO) {
                int psel = laneE ? pe : po;
                if (!liveO) psel = pe;
                if (!liveE) psel = po;
                const int p8 = psel * 8;
                float acc = 0.f;
                #pragma unroll
                for (int q = 0; q < 7; ++q) {
                    unsigned short u = c2w[(OX + q) * C2ST + p8 + q];
                    acc += __builtin_bit_cast(float, ((unsigned)u) << 16);
                }
                if (liveE) w[3 - j] += laneE ? acc : 0.f;
                if (liveO) w[2 - j] += laneE ? 0.f : acc;
            }
        }

        // ---- close one output row + shift window ----
        if (i >= 6) {
            const int gyO = gy0 + A0 + i - 6;
            const int o = gyO * Wn + tx0 + OX;
            if (laneE) {
                float r = img[o] - w[0] - netb[o];
                rb[o] = r;
                rsq += r * r;
            }
        }
        w[0] = laneE ? w[1] : w[0];
        w[1] = laneE ? w[2] : w[1];
        w[2] = laneE ? w[3] : w[2];
        w[3] = laneE ? 0.f : w[3];
    };

    // prologue: fill gather set for row 0
    unsigned G[3][12], N[3][12];
    zg(A0, 0, G[0]);
    zg(A0, 1, G[1]);
    zg(A0, 2, G[2]);

    #pragma unroll 1
    for (int mi = 0; mi < NSUB / 2; ++mi) {
        subiter(2 * mi, true, G, N);       // consume G, prefetch into N
        subiter(2 * mi + 1, false, N, G);  // consume N, prefetch into G
    }

    rsq = waveReduceSum(rsq);
    if (lane == 0) s_red[wv] = rsq;
    __syncthreads();
    if (tid == 0) atomicAdd(&ws[WS_SUMSQ + bz], s_red[0] + s_red[1] + s_red[2] + s_red[3]);
}

__global__ __launch_bounds__(256) void finalize_kernel(const float* __restrict__ net,
                                                       const float* __restrict__ stdn,
                                                       const float* __restrict__ alpha,
                                                       const float* __restrict__ ws,
                                                       float* __restrict__ out) {
    const int b = blockIdx.y;
    const float sum = ws[WS_SUMSQ + b];
    const float k = __expf(alpha[0]) * stdn[b] * 256.0f;
    const float nr = sqrtf(sum);
    const float scale = fminf(1.0f, k / (nr + 1e-12f));
    const int base = b * (Hn * Wn) + (blockIdx.x * 256 + threadIdx.x) * 4;
    float4 rv = *(const float4*)(out + base);
    const float4 nv = *(const float4*)(net + base);
    float4 o;
    o.x = fmaf(rv.x, scale, nv.x);
    o.y = fmaf(rv.y, scale, nv.y);
    o.z = fmaf(rv.z, scale, nv.z);
    o.w = fmaf(rv.w, scale, nv.w);
    *(float4*)(out + base) = o;
}

extern "C" void kernel_launch(void* const* d_in, const int* in_sizes, int n_in,
                              void* d_out, int out_size, void* d_ws, size_t ws_size,
                              hipStream_t stream) {
    const float* input = (const float*)d_in[0];
    const float* stdn  = (const float*)d_in[1];
    const float* net   = (const float*)d_in[3];
    const float* cw    = (const float*)d_in[4];
    const float* sf    = (const float*)d_in[5];
    const float* alpha = (const float*)d_in[6];
    const float* rw    = (const float*)d_in[7];
    const float* rc    = (const float*)d_in[8];
    float* out = (float*)d_out;
    float* ws  = (float*)d_ws;

    setup_kernel<<<dim3(1 + 48 * 32), 256, 0, stream>>>(cw, sf, rw, rc, ws);
    fused_kernel<<<dim3(Wn / TW, Hn / STRIP, Bn), 256, 0, stream>>>(input, net, ws, out);
    finalize_kernel<<<dim3(64, Bn), 256, 0, stream>>>(net, stdn, alpha, ws, out);
}

// Round 14
// 157.314 us; speedup vs baseline: 1.0648x; 1.0648x over previous
//
#include <hip/hip_runtime.h>

// Problem constants
#define Bn   16
#define Fn   48
#define Hn   256
#define Wn   256
#define Mn   51

#define TW    32
#define STRIP 64            // output rows per block (4 waves x 16-row bands)
#define BAND  16            // output rows per wave
#define NSUB  22            // a-rows per wave (BAND + 6)
#define DUPR  77            // staged input rows (STRIP + 13)
#define DUP_S 55            // dup-array row stride in dwords
#define C2ST  58            // c2 row stride in shorts (dword stride 29, odd -> bank spread)
#define C2DW  29

// Workspace layout (floats)
#define WS_SUMSQ 0
#define WS_FRG   16                 // 14 tiles * 64 lanes * uint4 = 3584 floats
#define WS_TABB  3600               // filter-major bf16 LUT: tab[f][idx]
#define TAB_N    8001
#define TAB_S    8004

typedef short short8 __attribute__((ext_vector_type(8)));
typedef float f32x4 __attribute__((ext_vector_type(4)));

__device__ __forceinline__ float waveReduceSum(float v) {
    #pragma unroll
    for (int o = 32; o > 0; o >>= 1) v += __shfl_xor(v, o);
    return v;
}

__device__ __forceinline__ unsigned short f2bf(float x) {
    unsigned int u = __builtin_bit_cast(unsigned int, x);
    unsigned int r = (u + 0x7FFFu + ((u >> 16) & 1u)) >> 16;
    return (unsigned short)r;
}

// pack two f32 -> bf16x2 (round-half-up): 3 VALU ops via v_perm_b32
__device__ __forceinline__ unsigned pk_bf2(float lo, float hi) {
    unsigned ulo = __builtin_bit_cast(unsigned, lo) + 0x8000u;
    unsigned uhi = __builtin_bit_cast(unsigned, hi) + 0x8000u;
    return __builtin_amdgcn_perm(uhi, ulo, 0x07060302u);  // D = [uhi.hi16, ulo.hi16]
}

// ---- setup: block 0 = weight prep + MFMA fragments; blocks 1.. = filter-major RBF LUT ----
__global__ __launch_bounds__(256) void setup_kernel(const float* __restrict__ cw,
                                                    const float* __restrict__ sf,
                                                    const float* __restrict__ rw,
                                                    const float* __restrict__ rc,
                                                    float* __restrict__ ws) {
    const int tid = threadIdx.x;
    if (blockIdx.x == 0) {
        __shared__ float s_wn[Fn * 49];
        const int lane = tid & 63;
        const int wv = tid >> 6;
        for (int i = 0; i < 12; ++i) {
            int f = wv * 12 + i;
            float v = (lane < 49) ? cw[f * 49 + lane] : 0.f;
            float mean = waveReduceSum(v) * (1.0f / 49.0f);
            float c = (lane < 49) ? (v - mean) : 0.f;
            float nrm = sqrtf(waveReduceSum(c * c));
            if (lane < 49) s_wn[f * 49 + lane] = sf[f] * c / (nrm + 1e-12f);
        }
        if (tid < 16) ws[WS_SUMSQ + tid] = 0.f;
        __syncthreads();
        if (wv == 0) {
            const int quad = lane >> 4, l15 = lane & 15;
            uint4* frg = (uint4*)(ws + WS_FRG);
            // z-GEMM A: A[m=filter][k=tap2], tap2 = ky*8+kx
            for (int mt = 0; mt < 3; ++mt)
                for (int kt = 0; kt < 2; ++kt) {
                    unsigned int pk[4] = {0, 0, 0, 0};
                    int f = mt * 16 + l15;
                    for (int j = 0; j < 8; ++j) {
                        int k = kt * 32 + quad * 8 + j;
                        int ky = k >> 3, kx = k & 7;
                        float v = (ky < 7 && kx < 7) ? s_wn[f * 49 + ky * 7 + kx] : 0.f;
                        pk[j >> 1] |= (unsigned int)f2bf(v) << (16 * (j & 1));
                    }
                    frg[(mt * 2 + kt) * 64 + lane] = make_uint4(pk[0], pk[1], pk[2], pk[3]);
                }
            // c-GEMM A2: A2[m][k=filter], m = p*8+q (q==7 or m>=56 -> zero row)
            for (int mt = 0; mt < 4; ++mt)
                for (int kt = 0; kt < 2; ++kt) {
                    unsigned int pk[4] = {0, 0, 0, 0};
                    int m = mt * 16 + l15;
                    int p = m >> 3, q = m & 7;
                    for (int j = 0; j < 8; ++j) {
                        int f = kt * 32 + quad * 8 + j;
                        float v = (p < 7 && q < 7 && f < 48)
                                  ? s_wn[f * 49 + (6 - p) * 7 + (6 - q)] : 0.f;
                        pk[j >> 1] |= (unsigned int)f2bf(v) << (16 * (j & 1));
                    }
                    frg[(6 + mt * 2 + kt) * 64 + lane] = make_uint4(pk[0], pk[1], pk[2], pk[3]);
                }
        }
    } else {
        // filter-major LUT: tab[f*TAB_S + idx] = bf16(g_f(-100 + 0.025*idx))
        int b = blockIdx.x - 1;
        int f = b >> 5;
        int idx = ((b & 31) << 8) + tid;
        if (idx < TAB_N) {
            float x = -100.0f + 0.025f * (float)idx;
            float g = 0.f;
            for (int m = 0; m < Mn; ++m) {
                float d = x - rc[m];
                g += rw[f * Mn + m] * __expf(-0.01f * d * d);
            }
            unsigned short* tab = (unsigned short*)(ws + WS_TABB);
            tab[f * TAB_S + idx] = f2bf(g);
        }
    }
}

// ---- fused MFMA kernel: 16-row bands, deferred q-gather adds (read/add split) ----
__global__ __launch_bounds__(256) void fused_kernel(const float* __restrict__ input,
                                                    const float* __restrict__ net,
                                                    float* __restrict__ ws,
                                                    float* __restrict__ rout) {
    __shared__ unsigned int s_dup[DUPR * DUP_S];
    __shared__ __align__(16) unsigned short s_a[4][16 * 64];
    __shared__ __align__(8) unsigned short s_c2[4][48 * C2ST];   // per-wave [ax][m=p*8+q] bf16
    __shared__ float s_red[4];

    const int tid = threadIdx.x;
    const int lane = tid & 63;
    const int wv = tid >> 6;
    const int quad = lane >> 4;
    const int l15 = lane & 15;
    const int q4 = quad * 4;
    const int hl = lane >> 5;
    const int OX = lane & 31;
    const int bz = blockIdx.z;
    const int gy0 = blockIdx.y * STRIP;
    const int tx0 = blockIdx.x * TW;
    const float* img = input + bz * (Hn * Wn);
    const float* netb = net + bz * (Hn * Wn);
    float* rb = rout + bz * (Hn * Wn);

    // stage dup array: 77 rows x 55 dwords; dword i = (bf16 x[i], bf16 x[i+1]); sym pad
    for (int k = tid; k < DUPR * DUP_S; k += 256) {
        int j = k / DUP_S, i = k - j * DUP_S;
        int gy = gy0 - 6 + j;
        gy = (gy < 0) ? (-1 - gy) : ((gy > 255) ? (511 - gy) : gy);
        int gx0 = tx0 - 6 + i, gx1 = gx0 + 1;
        gx0 = (gx0 < 0) ? (-1 - gx0) : ((gx0 > 255) ? (511 - gx0) : gx0);
        gx1 = (gx1 < 0) ? (-1 - gx1) : ((gx1 > 255) ? (511 - gx1) : gx1);
        s_dup[j * DUP_S + i] = pk_bf2(img[gy * Wn + gx0], img[gy * Wn + gx1]);
    }
    // zero ALL of s_a (blocks 6..7 are MFMA B-operands never written; 0*garbage = NaN)
    {
        unsigned int* sa32 = (unsigned int*)s_a;
        for (int k = tid; k < 2048; k += 256) sa32[k] = 0u;
    }
    __syncthreads();

    // constant weight fragments
    const uint4* frg = (const uint4*)(ws + WS_FRG);
    short8 Afz[3][2], Afc[4][2];
    #pragma unroll
    for (int mt = 0; mt < 3; ++mt)
        #pragma unroll
        for (int kt = 0; kt < 2; ++kt)
            Afz[mt][kt] = __builtin_bit_cast(short8, frg[(mt * 2 + kt) * 64 + lane]);
    #pragma unroll
    for (int mt = 0; mt < 4; ++mt)
        #pragma unroll
        for (int kt = 0; kt < 2; ++kt)
            Afc[mt][kt] = __builtin_bit_cast(short8, frg[(6 + mt * 2 + kt) * 64 + lane]);

    const unsigned short* tab = (const unsigned short*)(ws + WS_TABB);
    const int fq = q4 * TAB_S;
    unsigned short* sa = s_a[wv];
    unsigned short* c2w = s_c2[wv];
    unsigned int* c2d = (unsigned int*)c2w;
    int wOff[3], rOff[2];
    #pragma unroll
    for (int mt = 0; mt < 3; ++mt)
        wOff[mt] = l15 * 64 + (((2 * mt + (quad >> 1)) ^ (l15 & 7)) * 8) + (quad & 1) * 4;
    #pragma unroll
    for (int kt = 0; kt < 2; ++kt)
        rOff[kt] = l15 * 64 + (((4 * kt + quad) ^ (l15 & 7)) * 8);

    const int A0 = wv * BAND;
    float w[4] = {0.f, 0.f, 0.f, 0.f};
    float rsq = 0.f;

    // zg: dup-reads -> z-MFMA -> issue 12 filter-major LUT gathers (results pend in g[])
    auto zg = [&](int aIdx, int nt, unsigned* g) {
        const int nt16 = nt * 16;
        const unsigned* dp0 = &s_dup[(aIdx + quad) * DUP_S + l15 + nt16];
        const unsigned* dp1 = dp0 + 4 * DUP_S;
        short8 B0 = __builtin_bit_cast(short8, make_uint4(dp0[0], dp0[2], dp0[4], dp0[6]));
        short8 B1 = __builtin_bit_cast(short8, make_uint4(dp1[0], dp1[2], dp1[4], dp1[6]));
        #pragma unroll
        for (int mt = 0; mt < 3; ++mt) {
            f32x4 z = {0.f, 0.f, 0.f, 0.f};
            z = __builtin_amdgcn_mfma_f32_16x16x32_bf16(Afz[mt][0], B0, z, 0, 0, 0);
            z = __builtin_amdgcn_mfma_f32_16x16x32_bf16(Afz[mt][1], B1, z, 0, 0, 0);
            #pragma unroll
            for (int r = 0; r < 4; ++r) {
                float tt = __builtin_amdgcn_fmed3f(
                    fmaf(z[r], 40.0f, 4000.5f), 0.0f, 8000.0f);
                g[mt * 4 + r] = tab[fq + (mt * 16 + r) * TAB_S + (int)tt];
            }
        }
    };

    // consume: pack -> s_a roundtrip -> convT MFMA -> C2 stores
    auto consume = [&](int nt, const unsigned* g, bool vy) {
        const int nt16 = nt * 16;
        const int ax = l15 + nt16;
        const unsigned msk = (vy && ((unsigned)(tx0 - 3 + ax) < (unsigned)Wn))
                             ? 0xFFFFFFFFu : 0u;
        #pragma unroll
        for (int mt = 0; mt < 3; ++mt) {
            unsigned lo = (g[mt * 4 + 0] | (g[mt * 4 + 1] << 16)) & msk;
            unsigned hi = (g[mt * 4 + 2] | (g[mt * 4 + 3] << 16)) & msk;
            *(uint2*)&sa[wOff[mt]] = make_uint2(lo, hi);
        }
        short8 B20 = *(const short8*)&sa[rOff[0]];
        short8 B21 = *(const short8*)&sa[rOff[1]];
        f32x4 d2[4];
        #pragma unroll
        for (int mt = 0; mt < 4; ++mt) {
            f32x4 c0 = {0.f, 0.f, 0.f, 0.f};
            c0 = __builtin_amdgcn_mfma_f32_16x16x32_bf16(Afc[mt][0], B20, c0, 0, 0, 0);
            c0 = __builtin_amdgcn_mfma_f32_16x16x32_bf16(Afc[mt][1], B21, c0, 0, 0, 0);
            d2[mt] = c0;
        }
        const int rowdw = ax * C2DW;
        #pragma unroll
        for (int mt = 0; mt < 4; ++mt) {
            unsigned lo = pk_bf2(d2[mt][0], d2[mt][1]);
            unsigned hi = pk_bf2(d2[mt][2], d2[mt][3]);
            const int cd = rowdw + mt * 8 + 2 * quad;
            if (mt < 3) {
                c2d[cd] = lo;
                c2d[cd + 1] = hi;
            } else if (quad < 2) {    // m=56..63 junk rows; cols would overflow stride
                c2d[cd] = lo;
                c2d[cd + 1] = hi;
            }
        }
    };

    // produce: full zg/consume for a-row i (r12's shallow interleave, unchanged)
    auto produce = [&](int i) {
        const int aIdx = A0 + i;
        const bool vy = ((unsigned)(gy0 - 3 + aIdx) < (unsigned)Hn);
        unsigned gA[12], gB[12];
        zg(aIdx, 0, gA);
        zg(aIdx, 1, gB);
        consume(0, gA, vy);
        zg(aIdx, 2, gA);
        consume(1, gB, vy);
        consume(2, gA, vy);
    };

    // qread: ISSUE the 28 q-gather u16 reads for subiter i into pend (no adds).
    // Safe to defer: same-wave DS ops are in-order, so these reads are ordered
    // before the NEXT produce's C2 writes.
    auto qread = [&](int i, bool even, unsigned* pend) {
        const bool laneE = even ? (hl == 0) : (hl != 0);
        #pragma unroll
        for (int j = 0; j < 4; ++j) {
            const int pe = 2 * j, po = 2 * j + 1;
            const bool liveE = (pe <= i) && (pe >= i - (BAND - 1));
            const bool liveO = (j < 3) && (po <= i) && (po >= i - (BAND - 1));
            if (liveE || liveO) {
                int psel = laneE ? pe : po;
                if (!liveO) psel = pe;
                if (!liveE) psel = po;
                const int p8 = psel * 8;
                #pragma unroll
                for (int q = 0; q < 7; ++q)
                    pend[j * 7 + q] = c2w[(OX + q) * C2ST + p8 + q];
            }
        }
    };

    // qadd: apply deferred adds for subiter i, close its output row, shift window
    auto qadd = [&](int i, bool even, const unsigned* pend) {
        const bool laneE = even ? (hl == 0) : (hl != 0);
        #pragma unroll
        for (int j = 0; j < 4; ++j) {
            const int pe = 2 * j, po = 2 * j + 1;
            const bool liveE = (pe <= i) && (pe >= i - (BAND - 1));
            const bool liveO = (j < 3) && (po <= i) && (po >= i - (BAND - 1));
            if (liveE || liveO) {
                float acc = 0.f;
                #pragma unroll
                for (int q = 0; q < 7; ++q)
                    acc += __builtin_bit_cast(float, pend[j * 7 + q] << 16);
                if (liveE) w[3 - j] += laneE ? acc : 0.f;
                if (liveO) w[2 - j] += laneE ? 0.f : acc;
            }
        }
        if (i >= 6) {
            const int gyO = gy0 + A0 + i - 6;
            const int o = gyO * Wn + tx0 + OX;
            if (laneE) {
                float r = img[o] - w[0] - netb[o];
                rb[o] = r;
                rsq += r * r;
            }
        }
        w[0] = laneE ? w[1] : w[0];
        w[1] = laneE ? w[2] : w[1];
        w[2] = laneE ? w[3] : w[2];
        w[3] = laneE ? 0.f : w[3];
    };

    // software pipeline: produce(i) ; qadd(i-1) [reads aged a full produce] ; qread(i)
    unsigned pend[28];
    produce(0);
    qread(0, true, pend);
    #pragma unroll 1
    for (int i = 1; i < NSUB; ++i) {
        const bool ev = (i & 1) == 0;
        produce(i);
        qadd(i - 1, !ev, pend);
        qread(i, ev, pend);
    }
    qadd(NSUB - 1, ((NSUB - 1) & 1) == 0, pend);

    rsq = waveReduceSum(rsq);
    if (lane == 0) s_red[wv] = rsq;
    __syncthreads();
    if (tid == 0) atomicAdd(&ws[WS_SUMSQ + bz], s_red[0] + s_red[1] + s_red[2] + s_red[3]);
}

__global__ __launch_bounds__(256) void finalize_kernel(const float* __restrict__ net,
                                                       const float* __restrict__ stdn,
                                                       const float* __restrict__ alpha,
                                                       const float* __restrict__ ws,
                                                       float* __restrict__ out) {
    const int b = blockIdx.y;
    const float sum = ws[WS_SUMSQ + b];
    const float k = __expf(alpha[0]) * stdn[b] * 256.0f;
    const float nr = sqrtf(sum);
    const float scale = fminf(1.0f, k / (nr + 1e-12f));
    const int base = b * (Hn * Wn) + (blockIdx.x * 256 + threadIdx.x) * 4;
    float4 rv = *(const float4*)(out + base);
    const float4 nv = *(const float4*)(net + base);
    float4 o;
    o.x = fmaf(rv.x, scale, nv.x);
    o.y = fmaf(rv.y, scale, nv.y);
    o.z = fmaf(rv.z, scale, nv.z);
    o.w = fmaf(rv.w, scale, nv.w);
    *(float4*)(out + base) = o;
}

extern "C" void kernel_launch(void* const* d_in, const int* in_sizes, int n_in,
                              void* d_out, int out_size, void* d_ws, size_t ws_size,
                              hipStream_t stream) {
    const float* input = (const float*)d_in[0];
    const float* stdn  = (const float*)d_in[1];
    const float* net   = (const float*)d_in[3];
    const float* cw    = (const float*)d_in[4];
    const float* sf    = (const float*)d_in[5];
    const float* alpha = (const float*)d_in[6];
    const float* rw    = (const float*)d_in[7];
    const float* rc    = (const float*)d_in[8];
    float* out = (float*)d_out;
    float* ws  = (float*)d_ws;

    setup_kernel<<<dim3(1 + 48 * 32), 256, 0, stream>>>(cw, sf, rw, rc, ws);
    fused_kernel<<<dim3(Wn / TW, Hn / STRIP, Bn), 256, 0, stream>>>(input, net, ws, out);
    finalize_kernel<<<dim3(64, Bn), 256, 0, stream>>>(net, stdn, alpha, ws, out);
}